// Round 16
// baseline (588.956 us; speedup 1.0000x reference)
//
#include <hip/hip_runtime.h>

// ---------------- problem constants ----------------
#define VOCAB 18
#define EMB   200
#define HID   200
#define G4    800           // 4*HID
#define SEQ   128
#define BATCH 2048
#define MB    16            // FULL M=16 tile -> every streamed weight byte used
#define NBLK  (BATCH/MB)    // 128 blocks
#define NT    56            // N tiles: 50 gate (j-blocked) + 2 logit + 4 zero
#define KS    7             // K steps of 32 -> 224 padded K
#define TPB   512           // 8 waves -> 2 waves/SIMD
#define TPW   7             // tiles per wave
#define LCH   64            // logit chunk (steps buffered in LDS)
#define SV    (SEQ*VOCAB)   // 2304
#define LOGITS_N ((size_t)BATCH*SEQ*VOCAB)

typedef short s16x8 __attribute__((ext_vector_type(8)));
typedef float f32x4 __attribute__((ext_vector_type(4)));

__device__ __forceinline__ unsigned short f2bf(float f) {
  unsigned int u = __float_as_uint(f);
  u += 0x7FFFu + ((u >> 16) & 1u);
  return (unsigned short)(u >> 16);
}
__device__ __forceinline__ float sigm(float x) {
  float e = __builtin_amdgcn_exp2f(x * 1.4426950408889634f);
  return e * __builtin_amdgcn_rcpf(e + 1.0f);
}
__device__ __forceinline__ float tanhq(float x) {
  float e = __builtin_amdgcn_exp2f(x * 2.8853900817779268f);
  return 1.0f - 2.0f * __builtin_amdgcn_rcpf(e + 1.0f);
}
// one-hot/bias slot in a buffer for B[k][col c], k in [192,224):
__device__ __forceinline__ int oh_elem(int c, int k) {
  return (384 + ((k >> 3) & 3) * 16 + c) * 8 + (k & 7);
}

// ---------------- prep 1 (unchanged): token table, gate-major cols ----------
__global__ void prep_tbl(const float* __restrict__ E, const float* __restrict__ W_ih,
                         const float* __restrict__ b_ih, const float* __restrict__ b_hh,
                         unsigned short* __restrict__ tbl) {
  int tid = blockIdx.x * 256 + threadIdx.x;
  if (tid >= VOCAB * G4) return;
  int v = tid / G4, col = tid % G4;
  float s = b_ih[col] + b_hh[col];
  if (v != 0) {
    const float* Er = E + v * EMB;
    const float* Wr = W_ih + col * EMB;
    for (int e = 0; e < EMB; ++e) s += Er[e] * Wr[e];
  }
  tbl[tid] = f2bf(s);
}

// ---------------- prep 2 (unchanged): Wp as MFMA A-operand ----------------
// A-frag: lane l elem i = A[rr=l&15][k=32s+8*(l>>4)+i].
// Gate tiles n<50: rr=4*jj+g -> gate g of j=4n+jj (colg=g*200+j):
//   A = W_hh[colg*HID+k] (k<200) | tbl[k-201][colg] (201<=k<219) | 0.
// Logit tiles n=50,51: rr=v-16(n-50): W_out (k<200) | b_out (k==200) | 0.
__global__ void prep_wp(const float* __restrict__ W_hh, const float* __restrict__ W_out,
                        const float* __restrict__ b_out,
                        const unsigned short* __restrict__ tbl,
                        short* __restrict__ Wp) {
  int u = blockIdx.x * 256 + threadIdx.x;
  if (u >= NT * KS * 64) return;
  int n    = u / (KS * 64);
  int rem  = u % (KS * 64);
  int s_   = rem >> 6;
  int lane = rem & 63;
  int rr   = lane & 15;
  int kb   = lane >> 4;
  s16x8 o;
  #pragma unroll
  for (int i = 0; i < 8; ++i) {
    int k = 32 * s_ + 8 * kb + i;
    short b = 0;
    if (n < 50) {
      int g = rr & 3, j = 4 * n + (rr >> 2);
      int colg = g * 200 + j;
      if (k < HID)                          b = (short)f2bf(W_hh[colg * HID + k]);
      else if (k >= 201 && k < 201 + VOCAB) b = (short)tbl[(k - 201) * G4 + colg];
    } else if (n < 52) {
      int v = 16 * (n - 50) + rr;
      if (v < VOCAB) {
        if (k < HID)       b = (short)f2bf(W_out[v * HID + k]);
        else if (k == HID) b = (short)f2bf(b_out[v]);
      }
    }
    o[i] = b;
  }
  *(s16x8*)(Wp + (size_t)u * 8) = o;
}

// ---------------- main ----------------
// 128 blocks x 16 rows (full M-tile: 2x reuse per streamed weight byte);
// 8 waves (2/SIMD), 7 tiles/wave. Swapped MFMA D = W(A) x h(B): lane = batch
// col c=l&15 (all 16 valid -> full-lane EW), regs q = 4 gates of j=4n+(l>>4).
// Double-buffered hA + ONE barrier/step. Logits buffered in 64-step chunks.
__global__ __launch_bounds__(TPB) __attribute__((amdgpu_waves_per_eu(2, 2)))
void lstm_kernel(const int* __restrict__ x, const short* __restrict__ Wp,
                 float* __restrict__ out) {
  __shared__ unsigned short hbuf[2][KS * 64 * 8];  // 2 x 7.2KB
  __shared__ int   xtok[MB * SEQ];                 // 8KB
  __shared__ float logL[MB * LCH * VOCAB];         // 73.7KB

  const int tid  = threadIdx.x;
  const int lane = tid & 63;
  const int w    = tid >> 6;                   // wave 0..7
  const int blk  = blockIdx.x;
  const int c    = lane & 15;                  // batch row (all valid)
  const int kb   = lane >> 4;                  // jj within tile / reg quadrant

  // init both buffers: h=0, bf16 1.0 at bias row k=200 cols 0..15
  for (int i = tid; i < KS * 64 * 8; i += TPB) {
    unsigned short v = (i >= 3200 && i < 3328 && (i & 7) == 0) ? (unsigned short)0x3F80
                                                               : (unsigned short)0;
    hbuf[0][i] = v; hbuf[1][i] = v;
  }
  for (int i = tid; i < MB * SEQ; i += TPB) xtok[i] = x[blk * (MB * SEQ) + i];

  // weight fragments (wave 7 loads only its 3 used tiles: 49 gate + 50,51 logit)
  s16x8 wf[TPW][KS];
  #pragma unroll
  for (int n = 0; n < TPW; ++n) {
    if (w < 7 || n < 3) {
      #pragma unroll
      for (int s = 0; s < KS; ++s) {
        wf[n][s] = *(const s16x8*)(Wp + ((((w * TPW + n) * KS) + s) * 64 + lane) * 8);
        asm volatile("" : "+a"(wf[n][s]));
      }
      asm volatile("" ::: "memory");
    }
  }

  __syncthreads();
  if (tid < MB) hbuf[0][oh_elem(tid, 201 + xtok[tid * SEQ])] = 0x3F80;

  float cc[TPW] = {0, 0, 0, 0, 0, 0, 0};
  const f32x4 zz = {0.f, 0.f, 0.f, 0.f};
  __syncthreads();

#define EW_ONE(V, CC, J) {                                                      \
    float i_ = sigm(V[0]), f_ = sigm(V[1]), g_ = tanhq(V[2]), o_ = sigm(V[3]);  \
    float cn = f_ * (CC) + i_ * g_;                                             \
    float h  = o_ * tanhq(cn);                                                  \
    (CC) = cn;                                                                  \
    hnxt[(((J) >> 5) * 64 + 16 * (((J) >> 3) & 3) + c) * 8 + ((J) & 7)] = f2bf(h); \
    if (t == SEQ - 1) {                                                         \
      size_t bg = (size_t)blk * MB + c;                                         \
      out[LOGITS_N + bg * HID + (J)] = h;                                       \
      out[LOGITS_N + (size_t)BATCH * HID + bg * HID + (J)] = cn;                \
    } }

  auto flush = [&](int base) {            // copy logL chunk -> out
    for (int u = tid * 4; u < MB * LCH * VOCAB; u += TPB * 4) {
      int cr = u / (LCH * VOCAB);
      int off = u - cr * (LCH * VOCAB);
      *(f32x4*)&out[((size_t)blk * MB + cr) * SV + base * VOCAB + off] =
          *(const f32x4*)&logL[u];
    }
  };

  #pragma unroll 1
  for (int t = 0; t < SEQ; ++t) {
    if (t == LCH + 1) { flush(0); __syncthreads(); }   // TT 0..63 complete

    const unsigned short* hcur = hbuf[t & 1];
    unsigned short* hnxt = hbuf[(t + 1) & 1];

    if (w < 7) {
      {   // group 0: tiles p=0..3
        s16x8 aF[KS];
        #pragma unroll
        for (int s = 0; s < KS; ++s) aF[s] = *(const s16x8*)&hcur[(s * 64 + lane) * 8];
        f32x4 a0 = zz, a1 = zz, a2 = zz, a3 = zz;
        #pragma unroll
        for (int s = 0; s < KS; ++s) {
          a0 = __builtin_amdgcn_mfma_f32_16x16x32_bf16(wf[0][s], aF[s], a0, 0, 0, 0);
          a1 = __builtin_amdgcn_mfma_f32_16x16x32_bf16(wf[1][s], aF[s], a1, 0, 0, 0);
          a2 = __builtin_amdgcn_mfma_f32_16x16x32_bf16(wf[2][s], aF[s], a2, 0, 0, 0);
          a3 = __builtin_amdgcn_mfma_f32_16x16x32_bf16(wf[3][s], aF[s], a3, 0, 0, 0);
        }
        int J0 = 28 * w + kb;
        EW_ONE(a0, cc[0], J0);
        EW_ONE(a1, cc[1], J0 + 4);
        EW_ONE(a2, cc[2], J0 + 8);
        EW_ONE(a3, cc[3], J0 + 12);
      }
      {   // group 1: tiles p=4..6
        s16x8 aF[KS];
        #pragma unroll
        for (int s = 0; s < KS; ++s) aF[s] = *(const s16x8*)&hcur[(s * 64 + lane) * 8];
        f32x4 a0 = zz, a1 = zz, a2 = zz;
        #pragma unroll
        for (int s = 0; s < KS; ++s) {
          a0 = __builtin_amdgcn_mfma_f32_16x16x32_bf16(wf[4][s], aF[s], a0, 0, 0, 0);
          a1 = __builtin_amdgcn_mfma_f32_16x16x32_bf16(wf[5][s], aF[s], a1, 0, 0, 0);
          a2 = __builtin_amdgcn_mfma_f32_16x16x32_bf16(wf[6][s], aF[s], a2, 0, 0, 0);
        }
        int J0 = 28 * w + 16 + kb;
        EW_ONE(a0, cc[4], J0);
        EW_ONE(a1, cc[5], J0 + 4);
        EW_ONE(a2, cc[6], J0 + 8);
      }
    } else {
      // wave 7: gate tile 49 (local 0) + logit tiles 50,51 (local 1,2)
      s16x8 aF[KS];
      #pragma unroll
      for (int s = 0; s < KS; ++s) aF[s] = *(const s16x8*)&hcur[(s * 64 + lane) * 8];
      f32x4 a0 = zz, a1 = zz, a2 = zz;
      #pragma unroll
      for (int s = 0; s < KS; ++s) {
        a0 = __builtin_amdgcn_mfma_f32_16x16x32_bf16(wf[0][s], aF[s], a0, 0, 0, 0);
        a1 = __builtin_amdgcn_mfma_f32_16x16x32_bf16(wf[1][s], aF[s], a1, 0, 0, 0);
        a2 = __builtin_amdgcn_mfma_f32_16x16x32_bf16(wf[2][s], aF[s], a2, 0, 0, 0);
      }
      int J0 = 196 + kb;
      EW_ONE(a0, cc[0], J0);
      if (t > 0) {                          // logits for step t-1, chunked
        int slot = (t - 1) & (LCH - 1);
        int vg = 4 * kb;
        #pragma unroll
        for (int q = 0; q < 4; ++q) {
          logL[c * (LCH * VOCAB) + slot * VOCAB + vg + q] = a1[q];
          if (vg + q < 2)
            logL[c * (LCH * VOCAB) + slot * VOCAB + 16 + vg + q] = a2[q];
        }
      }
    }
    // one-hot advance into hnxt: clear tok[t-1] (same-parity buffer), set tok[t+1]
    if (tid < MB && t + 1 < SEQ) {
      if (t >= 1) hnxt[oh_elem(tid, 201 + xtok[tid * SEQ + t - 1])] = 0;
      hnxt[oh_elem(tid, 201 + xtok[tid * SEQ + t + 1])] = 0x3F80;
    }
    __syncthreads();                        // the ONLY per-step barrier
  }

  // ---- epilogue: logits for t=SEQ-1 from h_SEQ (in hbuf[0]); stale one-hot
  // rows hit zeroed logit-tile A-cols, harmless ----
  if (w == 7) {
    s16x8 aF[KS];
    #pragma unroll
    for (int s = 0; s < KS; ++s) aF[s] = *(const s16x8*)&hbuf[SEQ & 1][(s * 64 + lane) * 8];
    f32x4 a1 = zz, a2 = zz;
    #pragma unroll
    for (int s = 0; s < KS; ++s) {
      a1 = __builtin_amdgcn_mfma_f32_16x16x32_bf16(wf[1][s], aF[s], a1, 0, 0, 0);
      a2 = __builtin_amdgcn_mfma_f32_16x16x32_bf16(wf[2][s], aF[s], a2, 0, 0, 0);
    }
    int slot = (SEQ - 1) & (LCH - 1);
    int vg = 4 * kb;
    #pragma unroll
    for (int q = 0; q < 4; ++q) {
      logL[c * (LCH * VOCAB) + slot * VOCAB + vg + q] = a1[q];
      if (vg + q < 2)
        logL[c * (LCH * VOCAB) + slot * VOCAB + 16 + vg + q] = a2[q];
    }
  }
  __syncthreads();
  flush(LCH);                               // TT 64..127

#undef EW_ONE
}

extern "C" void kernel_launch(void* const* d_in, const int* in_sizes, int n_in,
                              void* d_out, int out_size, void* d_ws, size_t ws_size,
                              hipStream_t stream) {
  const int*   x     = (const int*)  d_in[0];
  const float* E     = (const float*)d_in[1];
  const float* W_ih  = (const float*)d_in[2];
  const float* W_hh  = (const float*)d_in[3];
  const float* b_ih  = (const float*)d_in[4];
  const float* b_hh  = (const float*)d_in[5];
  const float* W_out = (const float*)d_in[6];
  const float* b_out = (const float*)d_in[7];
  float* out = (float*)d_out;

  unsigned short* tbl = (unsigned short*)d_ws;
  short* Wp = (short*)d_ws + VOCAB * G4;

  prep_tbl<<<(VOCAB * G4 + 255) / 256, 256, 0, stream>>>(E, W_ih, b_ih, b_hh, tbl);
  prep_wp<<<(NT * KS * 64 + 255) / 256, 256, 0, stream>>>(W_hh, W_out, b_out, tbl, Wp);
  lstm_kernel<<<NBLK, TPB, 0, stream>>>(x, Wp, out);
}